// Round 5
// baseline (1870.812 us; speedup 1.0000x reference)
//
#include <hip/hip_runtime.h>
#include <math.h>

#define NLVL  16
#define TSZ   (1u << 19)
#define TMASK (TSZ - 1u)

typedef float v2f __attribute__((ext_vector_type(2)));

struct ResArr { int m1[NLVL * 4]; };  // per level, per dim: res-1

// ---------------------------------------------------------------------------
// Encode: one (point, level) per thread, LEVEL-MAJOR grid (keeps each XCD's
// L2 resident on one 4 MB level table; round-4 measured FETCH 5.85->0.72 GB).
// Round-4 showed 830 us at VALUBusy 8% = L2-request-rate bound (1.9 cyc/lane
// request). Corner-pair trick: PRIMES[0]==1 so corners (c0, c0+1) hash to
// {h, h^1} when c0 is even -> one aligned float4 covers both. Branchless:
// load the aligned pair for each corner, select by h&1; even case's 2nd load
// hits the just-filled L1 line -> expected L2 requests 16 -> 12 per point.
// Clamps dropped: x in [0,1) => bi in [0,res-2], bi+1 <= res-1, never clamped.
// ---------------------------------------------------------------------------
__global__ __launch_bounds__(256, 4)
void ingp_encode(const float4* __restrict__ x,
                 const float2* __restrict__ table,
                 float2*       __restrict__ feat,   // [NLVL][N] level-major
                 int N, int chunksPerLevel, ResArr res)
{
    const int l     = blockIdx.x / chunksPerLevel;
    const int chunk = blockIdx.x - l * chunksPerLevel;
    const int n     = chunk * 256 + threadIdx.x;
    if (n >= N) return;

    const float4 xv = x[n];
    const float px[4] = {xv.x, xv.y, xv.z, xv.w};

    int   bi[4];
    float fr[4], om[4];
    #pragma unroll
    for (int d = 0; d < 4; ++d) {
        const int r = res.m1[l * 4 + d];       // wave-uniform -> scalar
        const float pos = px[d] * (float)r;
        const float fb  = floorf(pos);
        fr[d] = pos - fb;
        om[d] = 1.0f - fr[d];
        bi[d] = (int)fb;
    }
    const float4* tl4 = (const float4*)(table + (size_t)l * TSZ);

    const unsigned hx0 = (unsigned)bi[0];       // prime for dim0 is 1
    const unsigned hx1 = (unsigned)(bi[0] + 1);

    float2 fv[16];
    float  wt[16];
    #pragma unroll
    for (int p = 0; p < 8; ++p) {              // p = bits (dim1,dim2,dim3)
        const int c1 = bi[1] + ( p       & 1);
        const int c2 = bi[2] + ((p >> 1) & 1);
        const int c3 = bi[3] + ((p >> 2) & 1);
        const unsigned rest = ((unsigned)c1 * 2654435761u)
                            ^ ((unsigned)c2 * 805459861u)
                            ^ ((unsigned)c3 * 3674653429u);
        const unsigned hA = (hx0 ^ rest) & TMASK;   // corner dim0-offset 0
        const unsigned hB = (hx1 ^ rest) & TMASK;   // corner dim0-offset 1
        const float4 qA = tl4[hA >> 1];
        const float4 qB = tl4[hB >> 1];
        float2 eA, eB;
        eA.x = (hA & 1) ? qA.z : qA.x;
        eA.y = (hA & 1) ? qA.w : qA.y;
        eB.x = (hB & 1) ? qB.z : qB.x;
        eB.y = (hB & 1) ? qB.w : qB.y;
        fv[2 * p]     = eA;
        fv[2 * p + 1] = eB;
        // weight product in the exact reference order: d0, then *=d1,d2,d3
        float wA = om[0];
        wA *= ( p       & 1) ? fr[1] : om[1];
        wA *= ((p >> 1) & 1) ? fr[2] : om[2];
        wA *= ((p >> 2) & 1) ? fr[3] : om[3];
        float wB = fr[0];
        wB *= ( p       & 1) ? fr[1] : om[1];
        wB *= ((p >> 1) & 1) ? fr[2] : om[2];
        wB *= ((p >> 2) & 1) ? fr[3] : om[3];
        wt[2 * p]     = wA;
        wt[2 * p + 1] = wB;
    }

    float a0 = 0.0f, a1 = 0.0f;
    #pragma unroll
    for (int c = 0; c < 16; ++c) {             // same c order as reference
        a0 = fmaf(wt[c], fv[c].x, a0);
        a1 = fmaf(wt[c], fv[c].y, a1);
    }
    feat[(size_t)l * N + n] = make_float2(a0, a1);
}

// ---------------------------------------------------------------------------
// MLP: one point per thread, fully unrolled. Output neurons packed in PAIRS
// (float2 ext-vector + elementwise fma) so the backend can emit v_pk_fma_f32
// (2x fp32/instr). Per-element accumulation chains keep the identical i-order
// -> bit-exact vs round-2 (absmax 0.0).
// ---------------------------------------------------------------------------
__global__ __launch_bounds__(256, 2)
void ingp_mlp(const float2* __restrict__ feat,   // [NLVL][N]
              const float*  __restrict__ w0,
              const float*  __restrict__ w1,
              const float*  __restrict__ w2,
              const float*  __restrict__ wout,
              const float*  __restrict__ bout,
              float*        __restrict__ out,
              int N)
{
    const int n = blockIdx.x * blockDim.x + threadIdx.x;
    if (n >= N) return;

    float2 f[NLVL];
    #pragma unroll
    for (int l = 0; l < NLVL; ++l) f[l] = feat[(size_t)l * N + n];  // coalesced

    v2f h1p[32];
    #pragma unroll
    for (int jp = 0; jp < 32; ++jp) h1p[jp] = (v2f){0.0f, 0.0f};
    #pragma unroll
    for (int l = 0; l < NLVL; ++l) {
        const v2f fx = {f[l].x, f[l].x};
        const v2f fy = {f[l].y, f[l].y};
        #pragma unroll
        for (int jp = 0; jp < 32; ++jp) {
            const v2f wlo = {w0[(2 * jp) * 32 + 2 * l],     w0[(2 * jp + 1) * 32 + 2 * l]};
            const v2f whi = {w0[(2 * jp) * 32 + 2 * l + 1], w0[(2 * jp + 1) * 32 + 2 * l + 1]};
            h1p[jp] = __builtin_elementwise_fma(wlo, fx,
                      __builtin_elementwise_fma(whi, fy, h1p[jp]));
        }
    }
    float h1s[64];
    #pragma unroll
    for (int jp = 0; jp < 32; ++jp) {
        h1s[2 * jp]     = fmaxf(h1p[jp].x, 0.0f);
        h1s[2 * jp + 1] = fmaxf(h1p[jp].y, 0.0f);
    }

    float h2s[64];
    #pragma unroll
    for (int jp = 0; jp < 32; ++jp) {
        v2f acc = {0.0f, 0.0f};
        const float* wr0 = w1 + (2 * jp) * 64;
        const float* wr1 = w1 + (2 * jp + 1) * 64;
        #pragma unroll
        for (int i = 0; i < 64; ++i) {
            const v2f wv = {wr0[i], wr1[i]};
            const v2f hv = {h1s[i], h1s[i]};
            acc = __builtin_elementwise_fma(wv, hv, acc);
        }
        h2s[2 * jp]     = fmaxf(acc.x, 0.0f);
        h2s[2 * jp + 1] = fmaxf(acc.y, 0.0f);
    }

    float h3s[64];
    #pragma unroll
    for (int jp = 0; jp < 32; ++jp) {
        v2f acc = {0.0f, 0.0f};
        const float* wr0 = w2 + (2 * jp) * 64;
        const float* wr1 = w2 + (2 * jp + 1) * 64;
        #pragma unroll
        for (int i = 0; i < 64; ++i) {
            const v2f wv = {wr0[i], wr1[i]};
            const v2f hv = {h2s[i], h2s[i]};
            acc = __builtin_elementwise_fma(wv, hv, acc);
        }
        h3s[2 * jp]     = fmaxf(acc.x, 0.0f);
        h3s[2 * jp + 1] = fmaxf(acc.y, 0.0f);
    }

    float o[3];
    #pragma unroll
    for (int k = 0; k < 3; ++k) {
        float acc = bout[k];
        const float* wr = wout + k * 64;
        #pragma unroll
        for (int i = 0; i < 64; ++i) acc = fmaf(wr[i], h3s[i], acc);
        o[k] = acc;
    }
    out[n * 3 + 0] = o[0];
    out[n * 3 + 1] = o[1];
    out[n * 3 + 2] = o[2];
}

// ---------------------------------------------------------------------------
// Fallback: round-2 fused kernel (used only if ws is too small for features).
// ---------------------------------------------------------------------------
__global__ __launch_bounds__(256, 2)
void ingp_fused(const float4* __restrict__ x,
                const float2* __restrict__ table,
                const float*  __restrict__ w0,
                const float*  __restrict__ w1,
                const float*  __restrict__ w2,
                const float*  __restrict__ wout,
                const float*  __restrict__ bout,
                float*        __restrict__ out,
                int N, ResArr res)
{
    const int n = blockIdx.x * blockDim.x + threadIdx.x;
    if (n >= N) return;

    const float4 xv = x[n];
    const float px[4] = {xv.x, xv.y, xv.z, xv.w};

    float h1[64];
    #pragma unroll
    for (int j = 0; j < 64; ++j) h1[j] = 0.0f;

    float a0p = 0.0f, a1p = 0.0f;

    #pragma unroll 1
    for (int l = 0; l < NLVL; ++l) {
        int   rm[4], bi[4];
        float fr[4], om[4];
        #pragma unroll
        for (int d = 0; d < 4; ++d) {
            const int r = res.m1[l * 4 + d];
            rm[d] = r;
            const float pos = px[d] * (float)r;
            const float fb  = floorf(pos);
            fr[d] = pos - fb;
            om[d] = 1.0f - fr[d];
            bi[d] = (int)fb;
        }
        const float2* tl = table + (size_t)l * TSZ;

        float2 fv[16];
        float  wt[16];
        #pragma unroll
        for (int c = 0; c < 16; ++c) {
            int c0 = bi[0] + ( c       & 1);
            int c1 = bi[1] + ((c >> 1) & 1);
            int c2 = bi[2] + ((c >> 2) & 1);
            int c3 = bi[3] + ((c >> 3) & 1);
            c0 = min(max(c0, 0), rm[0]);
            c1 = min(max(c1, 0), rm[1]);
            c2 = min(max(c2, 0), rm[2]);
            c3 = min(max(c3, 0), rm[3]);
            const unsigned hh = (unsigned)c0
                              ^ ((unsigned)c1 * 2654435761u)
                              ^ ((unsigned)c2 * 805459861u)
                              ^ ((unsigned)c3 * 3674653429u);
            fv[c] = tl[hh & TMASK];
            float w = ( c       & 1) ? fr[0] : om[0];
            w      *= ((c >> 1) & 1) ? fr[1] : om[1];
            w      *= ((c >> 2) & 1) ? fr[2] : om[2];
            w      *= ((c >> 3) & 1) ? fr[3] : om[3];
            wt[c] = w;
        }
        {
            const int lp = (l == 0) ? 0 : (l - 1);
            const float* w0c = w0 + 2 * lp;
            #pragma unroll
            for (int j = 0; j < 64; ++j)
                h1[j] = fmaf(w0c[j * 32], a0p, fmaf(w0c[j * 32 + 1], a1p, h1[j]));
        }
        float a0 = 0.0f, a1 = 0.0f;
        #pragma unroll
        for (int c = 0; c < 16; ++c) {
            a0 = fmaf(wt[c], fv[c].x, a0);
            a1 = fmaf(wt[c], fv[c].y, a1);
        }
        a0p = a0; a1p = a1;
    }
    {
        const float* w0c = w0 + 2 * (NLVL - 1);
        #pragma unroll
        for (int j = 0; j < 64; ++j)
            h1[j] = fmaf(w0c[j * 32], a0p, fmaf(w0c[j * 32 + 1], a1p, h1[j]));
    }
    #pragma unroll
    for (int j = 0; j < 64; ++j) h1[j] = fmaxf(h1[j], 0.0f);

    float h2[64];
    #pragma unroll
    for (int j = 0; j < 64; ++j) {
        float acc = 0.0f;
        const float* wr = w1 + j * 64;
        #pragma unroll
        for (int i = 0; i < 64; ++i) acc = fmaf(wr[i], h1[i], acc);
        h2[j] = fmaxf(acc, 0.0f);
    }
    float h3[64];
    #pragma unroll
    for (int j = 0; j < 64; ++j) {
        float acc = 0.0f;
        const float* wr = w2 + j * 64;
        #pragma unroll
        for (int i = 0; i < 64; ++i) acc = fmaf(wr[i], h2[i], acc);
        h3[j] = fmaxf(acc, 0.0f);
    }
    float o[3];
    #pragma unroll
    for (int k = 0; k < 3; ++k) {
        float acc = bout[k];
        const float* wr = wout + k * 64;
        #pragma unroll
        for (int i = 0; i < 64; ++i) acc = fmaf(wr[i], h3[i], acc);
        o[k] = acc;
    }
    out[n * 3 + 0] = o[0];
    out[n * 3 + 1] = o[1];
    out[n * 3 + 2] = o[2];
}

extern "C" void kernel_launch(void* const* d_in, const int* in_sizes, int n_in,
                              void* d_out, int out_size, void* d_ws, size_t ws_size,
                              hipStream_t stream) {
    (void)n_in; (void)out_size;

    const float* x     = (const float*)d_in[0];
    const float* table = (const float*)d_in[1];
    const float* w0    = (const float*)d_in[2];
    const float* w1    = (const float*)d_in[3];
    const float* w2    = (const float*)d_in[4];
    const float* wout  = (const float*)d_in[5];
    const float* bout  = (const float*)d_in[6];
    float* out = (float*)d_out;

    const int N = in_sizes[0] / 4;

    // Replicate numpy's float64 resolution computation bit-for-bit (same
    // glibc pow). Levels 5/10/15 of dim 3 sit on exact integer boundaries
    // (8^(5/15)==2), so floor() must see the same double as numpy produced.
    ResArr res;
    for (int d = 0; d < 4; ++d) {
        const double minr = 16.0;
        const double maxr = (d == 3) ? 128.0 : 256.0;
        const double growth = pow(maxr / minr, 1.0 / (double)(NLVL - 1));
        for (int l = 0; l < NLVL; ++l) {
            const int r = (int)floor(minr * pow(growth, (double)l));
            res.m1[l * 4 + d] = r - 1;
        }
    }

    const size_t featBytes = (size_t)NLVL * (size_t)N * sizeof(float2);

    if (ws_size >= featBytes) {
        float2* feat = (float2*)d_ws;
        const int chunksPerLevel = (N + 255) / 256;
        dim3 eg(NLVL * chunksPerLevel), eb(256);
        hipLaunchKernelGGL(ingp_encode, eg, eb, 0, stream,
                           (const float4*)x, (const float2*)table, feat,
                           N, chunksPerLevel, res);
        dim3 mg((N + 255) / 256), mb(256);
        hipLaunchKernelGGL(ingp_mlp, mg, mb, 0, stream,
                           feat, w0, w1, w2, wout, bout, out, N);
    } else {
        dim3 grid((N + 255) / 256), block(256);
        hipLaunchKernelGGL(ingp_fused, grid, block, 0, stream,
                           (const float4*)x, (const float2*)table,
                           w0, w1, w2, wout, bout, out, N, res);
    }
}